// Round 9
// baseline (283.020 us; speedup 1.0000x reference)
//
#include <hip/hip_runtime.h>

// Problem constants
#define BSEQ 64
#define LSEQ 512
#define CCH  1024
#define NT   7            // NUM_TAGS
#define NC   5            // real classes (labels are always 0..4)
#define NTOK (BSEQ*LSEQ)  // 32768
#define START_TAG 5
#define STOP_TAG  6
#define NEGV (-10000.0f)
#define GRID_LOGITS 1024  // fallback k_logits grid
#define FGRID 1024        // fused grid
#define FBLK  256
#define MAGIC 0x5A17C0DEu // flag "published" value (collides with no plausible poison)
#define CLAIM 0xC1A117EDu // ticket "claimed" value

// workspace layout (float indices). Flags/tickets strided 8 floats (32 B) to
// spread atomic RMWs across cache lines (R7 lesson: concentrated RMW traffic
// serialized ~100us).
#define WS_M   0          // [1024][32] chunk matrices (25 used per chunk)
#define WS_G   32768      // [1024] gold partials
#define WS_U   33792      // [64][8] u vectors (5 used)
#define WS_PS  34304      // [64] per-batch partial scores
#define WS_CF  34368      // [1024] chunk flags, stride 8
#define WS_FF  42560      // [64] fold flags, stride 8
#define WS_TK  43072      // [64] batch tickets, stride 8
#define WS_FT  43584      // final ticket
#define WS_TOT 43600

typedef float vfloat4 __attribute__((ext_vector_type(4)));

// ---- device-scope publish/consume (no reliance on cross-XCD L2 coherence) ----
__device__ __forceinline__ void ws_store(float* p, float v) {
    atomicExch((unsigned int*)p, __float_as_uint(v));
}
__device__ __forceinline__ float ws_load(float* p) {
    return __uint_as_float(atomicAdd((unsigned int*)p, 0u));
}
__device__ __forceinline__ unsigned flag_read(float* p) {
    return atomicAdd((unsigned int*)p, 0u);
}
__device__ __forceinline__ void flag_write(float* p, unsigned v) {
    atomicExch((unsigned int*)p, v);
}

// ---------------- DPP wave64 sum (result lands in lane 63) ----------------
template<int CTRL, int RMASK, int BMASK>
__device__ __forceinline__ float dpp_add(float x) {
    int y = __builtin_amdgcn_update_dpp(0, __float_as_int(x), CTRL, RMASK, BMASK, true);
    return x + __int_as_float(y);
}
__device__ __forceinline__ float wave_sum(float x) {
    x = dpp_add<0x111, 0xF, 0xF>(x);  // row_shr:1
    x = dpp_add<0x112, 0xF, 0xF>(x);  // row_shr:2
    x = dpp_add<0x114, 0xF, 0xF>(x);  // row_shr:4
    x = dpp_add<0x118, 0xF, 0xF>(x);  // row_shr:8
    x = dpp_add<0x142, 0xA, 0xF>(x);  // row_bcast:15 into rows 1,3
    x = dpp_add<0x143, 0xC, 0xF>(x);  // row_bcast:31 into rows 2,3 -> lane63 = total
    return x;
}

// 5-way log-sum-exp helper
__device__ __forceinline__ float lse5(const float v0, const float v1, const float v2,
                                      const float v3, const float v4) {
    float m = fmaxf(fmaxf(fmaxf(v0, v1), fmaxf(v2, v3)), v4);
    float s = __expf(v0 - m) + __expf(v1 - m) + __expf(v2 - m)
            + __expf(v3 - m) + __expf(v4 - m);
    return m + __logf(s);
}

// ================= FUSED kernel (single dispatch, ZERO waiting) =================
// R12 = R11 resubmitted byte-identical (R8 bench was an infra failure; this
// design cannot hang -- no spin loops, bounded work per block).
// R11 rationale: R7's spin-flag fusion ran at 126us with ZERO HBM traffic and
// 10.7% VALUBusy -> waves idle on concentrated atomic RMW polls. This version
// has NO spin anywhere: last-arriver-folds. Producer: publish -> own MAGIC
// flag -> ONE 16-flag sweep; all-set -> atomicExch ticket claim (poison-
// robust; the chronologically-last setter always sees all-16, so exactly one
// folder per batch). Same at level 2. Final claimer writes out[0] once and
// resets all flags/tickets to 0 (resets idempotent). Bounded one-shot atomic
// traffic, no CU-slot camping, no dispatch-order assumption (G16-safe).
// Fold math verbatim from R7 (correctness-verified there, absmax passed).
__global__ __launch_bounds__(256)
void k_fused(const float* __restrict__ X, const float* __restrict__ W,
             const float* __restrict__ bvec, const int* __restrict__ lab,
             const float* __restrict__ trans, float* __restrict__ out,
             float* __restrict__ ws)
{
    __shared__ float Wl[NT][CCH];   // 28 KB
    __shared__ float bl[NT];
    __shared__ float Tl[49];
    __shared__ float E_lds[32][5];  // this block's emissions (classes 0..4, incl bias)
    __shared__ float Msub[4*25];    // 4 sub-chunk matrices
    __shared__ float Cb[2*25];      // combine round 1

    const int tid  = threadIdx.x;
    const int lane = tid & 63;
    const int wv   = tid >> 6;      // 0..3
    const int bx   = blockIdx.x;
    const int sub  = bx & 15;       // chunk index within batch
    const int bat  = bx >> 4;

    vfloat4 xb[3][4];   // [phase-slot][row j]
    const size_t rbase = (size_t)bx * 32 + wv;       // + m*4, m=0..7

    #define ISSUE_PHASE(p, slot)                                                    \
        if ((p) < 8) {                                                              \
            const int G_ = (p) >> 2, k_ = (p) & 3;                                  \
            _Pragma("unroll")                                                       \
            for (int j = 0; j < 4; j++) {                                           \
                const size_t row_ = rbase + (size_t)((G_*4 + j) * 4);               \
                const vfloat4* xp_ = (const vfloat4*)(X + row_ * CCH) + (k_*64 + lane); \
                xb[slot][j] = __builtin_nontemporal_load(xp_);                      \
            }                                                                       \
        }

    ISSUE_PHASE(0, 0)
    ISSUE_PHASE(1, 1)

    {
        const vfloat4* W4  = (const vfloat4*)W;
        vfloat4*       Wl4 = (vfloat4*)(&Wl[0][0]);
        for (int i = tid; i < NT*CCH/4; i += FBLK) Wl4[i] = W4[i];
        if (tid < NT) bl[tid] = bvec[tid];
        if (tid < 49) Tl[tid] = trans[tid];
        const int gidx = bx * FBLK + tid;            // labels copy (blocks 0..127)
        if (gidx < NTOK) out[1 + gidx] = (float)lab[gidx];
    }
    __syncthreads();

    float* outP = out + 1 + NTOK;

    float acc[4][NT];
    #pragma unroll
    for (int j = 0; j < 4; j++)
        #pragma unroll
        for (int t = 0; t < NT; t++) acc[j][t] = 0.0f;

    #pragma unroll
    for (int p = 0; p < 8; ++p) {
        const int slot = p % 3;
        const int k    = p & 3;

        ISSUE_PHASE(p + 2, (p + 2) % 3)

        vfloat4 wreg[NT];
        {
            const int cb = (k*64 + lane) * 4;
            #pragma unroll
            for (int t = 0; t < NT; t++)
                wreg[t] = *(const vfloat4*)(&Wl[t][cb]);
        }

        #pragma unroll
        for (int j = 0; j < 4; j++) {
            #pragma unroll
            for (int t = 0; t < NT; t++) {
                acc[j][t] = fmaf(xb[slot][j].x, wreg[t].x,
                            fmaf(xb[slot][j].y, wreg[t].y,
                            fmaf(xb[slot][j].z, wreg[t].z,
                            fmaf(xb[slot][j].w, wreg[t].w, acc[j][t]))));
            }
        }

        if (k == 3) {
            const int G = p >> 2;
            #pragma unroll
            for (int j = 0; j < 4; j++) {
                const int m = G*4 + j;
                const size_t row = rbase + (size_t)(m * 4);
                const int rloc = wv + m*4;
                #pragma unroll
                for (int t = 0; t < NT; t++) {
                    float s = wave_sum(acc[j][t]);
                    if (lane == 63) {
                        const float e = s + bl[t];
                        outP[row * NT + t] = e;
                        if (t < NC) E_lds[rloc][t] = e;
                    }
                    acc[j][t] = 0.0f;
                }
            }
        }
    }
    #undef ISSUE_PHASE

    __syncthreads();   // E_lds complete

    // ---------------- per-block CRF chunk work (waves specialize) ----------------
    if (wv == 0) {
        if (lane < 20) {
            const int sc = lane / 5, basis = lane - sc*5;
            float TR[25];
            #pragma unroll
            for (int j = 0; j < NC; j++)
                #pragma unroll
                for (int k = 0; k < NC; k++) TR[j*5+k] = Tl[j*7+k];
            float fv[5];
            #pragma unroll
            for (int j = 0; j < NC; j++) fv[j] = (j == basis) ? 0.0f : NEGV;
            const int s0 = (sub == 0 && sc == 0) ? 1 : sc*8;  // batch token 0 via u
            const int s1 = sc*8 + 8;
            for (int s = s0; s < s1; ++s) {
                float fn[5];
                #pragma unroll
                for (int j = 0; j < NC; j++)
                    fn[j] = lse5(fv[0]+TR[j*5+0], fv[1]+TR[j*5+1], fv[2]+TR[j*5+2],
                                 fv[3]+TR[j*5+3], fv[4]+TR[j*5+4]) + E_lds[s][j];
                #pragma unroll
                for (int j = 0; j < NC; j++) fv[j] = fn[j];
            }
            #pragma unroll
            for (int j = 0; j < NC; j++) Msub[sc*25 + basis*5 + j] = fv[j];
        }
        if (lane < 50) {
            const int pp = lane / 25, r = lane - pp*25, i = r/5, jj = r - (r/5)*5;
            const float* A = &Msub[(2*pp)*25 + i*5];
            const float* B = &Msub[(2*pp+1)*25 + jj];
            Cb[pp*25 + r] = lse5(A[0]+B[0], A[1]+B[5], A[2]+B[10], A[3]+B[15], A[4]+B[20]);
        }
        if (lane < 25) {
            const int i = lane/5, jj = lane - i*5;
            const float* A = &Cb[i*5];
            const float* B = &Cb[25 + jj];
            ws_store(&ws[WS_M + (size_t)bx*32 + lane],
                     lse5(A[0]+B[0], A[1]+B[5], A[2]+B[10], A[3]+B[15], A[4]+B[20]));
        }
    } else if (wv == 1) {
        float g = 0.0f;
        if (lane < 32) {
            const int lg = bx*32 + lane;
            const int t  = lab[lg];
            const int tp = ((lg & (LSEQ-1)) == 0) ? START_TAG : lab[lg - 1];
            g = E_lds[lane][t] + Tl[t*7 + tp];
        }
        float gs = wave_sum(g);
        if (lane == 63) ws_store(&ws[WS_G + bx], gs);
    } else if (wv == 2) {
        if (sub == 0 && lane < NC)
            ws_store(&ws[WS_U + bat*8 + lane], Tl[lane*7 + START_TAG] + E_lds[0][lane]);
    }

    __syncthreads();   // all publishes of this block drained (barrier waits vmcnt)

    // ---------------- zero-wait completion detection (wave 0 only) ----------------
    if (wv != 0) return;

    // set own chunk flag, then sweep the batch's 16 flags ONCE
    if (lane == 0) {
        __threadfence();
        flag_write(&ws[WS_CF + bx*8], MAGIC);
        __threadfence();
    }
    unsigned f = (lane < 16) ? flag_read(&ws[WS_CF + (bat*16 + lane)*8]) : MAGIC;
    if (!__all(f == MAGIC)) return;   // not last arriver; someone later folds

    // claim the batch fold ticket (poison-robust: any old != CLAIM wins)
    unsigned old = 0;
    if (lane == 0) old = atomicExch((unsigned int*)&ws[WS_TK + bat*8], CLAIM);
    old = __shfl(old, 0);
    if (old == CLAIM) return;         // another block already folding this batch
    __threadfence();

    // ---- level-1 fold (verbatim R7-verified shfl math) ----
    float Mm[16];
    #pragma unroll
    for (int m = 0; m < 16; ++m)
        Mm[m] = (lane < 25) ? ws_load(&ws[WS_M + ((size_t)bat*16 + m)*32 + lane]) : 0.0f;

    float gp = (lane < 16) ? ws_load(&ws[WS_G + bat*16 + lane]) : 0.0f;
    float gtot = wave_sum(gp);
    gtot = __shfl(gtot, 63);

    float fvr = (lane < NC) ? ws_load(&ws[WS_U + bat*8 + lane]) : 0.0f;
    #pragma unroll
    for (int m = 0; m < 16; ++m) {
        const float f0 = __shfl(fvr, 0), f1 = __shfl(fvr, 1), f2 = __shfl(fvr, 2),
                    f3 = __shfl(fvr, 3), f4 = __shfl(fvr, 4);
        const float t0 = __shfl(Mm[m], 0*5 + lane);
        const float t1 = __shfl(Mm[m], 1*5 + lane);
        const float t2 = __shfl(Mm[m], 2*5 + lane);
        const float t3 = __shfl(Mm[m], 3*5 + lane);
        const float t4 = __shfl(Mm[m], 4*5 + lane);
        fvr = lse5(f0 + t0, f1 + t1, f2 + t2, f3 + t3, f4 + t4);
    }
    const float v0 = __shfl(fvr, 0), v1 = __shfl(fvr, 1), v2 = __shfl(fvr, 2),
                v3 = __shfl(fvr, 3), v4 = __shfl(fvr, 4);
    if (lane == 0) {
        float fwd = lse5(v0 + Tl[STOP_TAG*7+0], v1 + Tl[STOP_TAG*7+1],
                         v2 + Tl[STOP_TAG*7+2], v3 + Tl[STOP_TAG*7+3],
                         v4 + Tl[STOP_TAG*7+4]);
        float gold = gtot + Tl[STOP_TAG*7 + lab[bat*LSEQ + LSEQ - 1]];
        ws_store(&ws[WS_PS + bat], fwd - gold);
    }
    // reset this batch's chunk flags (safe: ticket stays CLAIM -> no dup folds)
    if (lane < 16) flag_write(&ws[WS_CF + (bat*16 + lane)*8], 0u);

    // set own fold flag, sweep all 64 ONCE
    if (lane == 0) {
        __threadfence();
        flag_write(&ws[WS_FF + bat*8], MAGIC);
        __threadfence();
    }
    unsigned f2 = flag_read(&ws[WS_FF + lane*8]);
    if (!__all(f2 == MAGIC)) return;  // not last folder

    unsigned o2 = 0;
    if (lane == 0) o2 = atomicExch((unsigned int*)&ws[WS_FT], CLAIM);
    o2 = __shfl(o2, 0);
    if (o2 == CLAIM) return;          // another folder is finishing
    __threadfence();

    // ---- level-2: sum 64 partials, single write of the score ----
    float ps = ws_load(&ws[WS_PS + lane]);
    float tot = wave_sum(ps);
    if (lane == 63) out[0] = tot;

    // cleanup for next iteration (idempotent zero-writes; dupes harmless)
    flag_write(&ws[WS_FF + lane*8], 0u);
    flag_write(&ws[WS_TK + lane*8], 0u);
    if (lane == 0) flag_write(&ws[WS_FT], 0u);
}

// ================= FALLBACK path (proven R3 two-kernel) =================
__global__ __launch_bounds__(256)
void k_logits(const float* __restrict__ X, const float* __restrict__ W,
              const float* __restrict__ bvec, const int* __restrict__ lab,
              float* __restrict__ out)
{
    __shared__ float Wl[NT][CCH];
    __shared__ float bl[NT];

    const int lane = threadIdx.x & 63;
    const int wid  = (blockIdx.x * 256 + threadIdx.x) >> 6;
    const int nw   = (GRID_LOGITS * 256) >> 6;

    vfloat4 xb[3][4];

    #define ISSUE_PHASE(p, slot)                                                   \
        if ((p) < 8) {                                                             \
            const int G_ = (p) >> 2, k_ = (p) & 3;                                 \
            _Pragma("unroll")                                                      \
            for (int j = 0; j < 4; j++) {                                          \
                const size_t row_ = (size_t)(wid + (G_*4 + j) * nw);               \
                const vfloat4* xp_ = (const vfloat4*)(X + row_ * CCH) + (k_*64 + lane); \
                xb[slot][j] = __builtin_nontemporal_load(xp_);                     \
            }                                                                      \
        }

    ISSUE_PHASE(0, 0)
    ISSUE_PHASE(1, 1)

    {
        const vfloat4* W4  = (const vfloat4*)W;
        vfloat4*       Wl4 = (vfloat4*)(&Wl[0][0]);
        for (int i = threadIdx.x; i < NT*CCH/4; i += 256) Wl4[i] = W4[i];
        if (threadIdx.x < NT) bl[threadIdx.x] = bvec[threadIdx.x];
    }
    __syncthreads();

    float* outP = out + 1 + NTOK;

    float acc[4][NT];
    #pragma unroll
    for (int j = 0; j < 4; j++)
        #pragma unroll
        for (int t = 0; t < NT; t++) acc[j][t] = 0.0f;

    #pragma unroll
    for (int p = 0; p < 8; ++p) {
        const int slot = p % 3;
        const int k    = p & 3;

        ISSUE_PHASE(p + 2, (p + 2) % 3)

        vfloat4 wreg[NT];
        {
            const int cb = (k*64 + lane) * 4;
            #pragma unroll
            for (int t = 0; t < NT; t++)
                wreg[t] = *(const vfloat4*)(&Wl[t][cb]);
        }

        #pragma unroll
        for (int j = 0; j < 4; j++) {
            #pragma unroll
            for (int t = 0; t < NT; t++) {
                acc[j][t] = fmaf(xb[slot][j].x, wreg[t].x,
                            fmaf(xb[slot][j].y, wreg[t].y,
                            fmaf(xb[slot][j].z, wreg[t].z,
                            fmaf(xb[slot][j].w, wreg[t].w, acc[j][t]))));
            }
        }

        if (k == 3) {
            const int G = p >> 2;
            #pragma unroll
            for (int j = 0; j < 4; j++) {
                const size_t row = (size_t)(wid + (G*4 + j) * nw);
                #pragma unroll
                for (int t = 0; t < NT; t++) {
                    float s = wave_sum(acc[j][t]);
                    if (lane == 63) outP[row * NT + t] = s + bl[t];
                    acc[j][t] = 0.0f;
                }
            }
        }
    }
    #undef ISSUE_PHASE

    for (int i = blockIdx.x * 256 + threadIdx.x; i < NTOK; i += GRID_LOGITS * 256)
        out[1 + i] = (float)lab[i];
    if (blockIdx.x == 0 && threadIdx.x == 0) out[0] = 0.0f;
}

__global__ __launch_bounds__(320)
void k_crf(const float* __restrict__ dout_ro, const int* __restrict__ lab,
           const float* __restrict__ trans, float* __restrict__ score)
{
    __shared__ float E[LSEQ*NT];
    __shared__ float M2[32*25];
    __shared__ float T[49];
    __shared__ float u_sh[NC];
    __shared__ float gred[5];

    const int b   = blockIdx.x;
    const int tid = threadIdx.x;
    const float* feats = dout_ro + 1 + NTOK + (size_t)b * (LSEQ*NT);

    for (int i = tid; i < LSEQ*NT; i += 320) E[i] = feats[i];
    if (tid < 49) T[tid] = trans[tid];
    __syncthreads();

    if (tid < NC) u_sh[tid] = T[tid*NT + START_TAG] + E[tid];

    float g = 0.0f;
    for (int l = tid; l < LSEQ; l += 320) {
        const int t  = lab[b*LSEQ + l];
        const int tp = (l == 0) ? START_TAG : lab[b*LSEQ + l - 1];
        g += E[l*NT + t] + T[t*NT + tp];
    }
    if (tid == 0) g += T[STOP_TAG*NT + lab[b*LSEQ + LSEQ - 1]];
    {
        float gs = wave_sum(g);
        if ((tid & 63) == 63) gred[tid >> 6] = gs;
    }

    float TR[NC*NC];
    #pragma unroll
    for (int j = 0; j < NC; j++)
        #pragma unroll
        for (int k = 0; k < NC; k++) TR[j*NC + k] = T[j*NT + k];

    const int chunk = tid / NC;
    const int basis = tid - chunk * NC;
    float fv[NC];
    #pragma unroll
    for (int j = 0; j < NC; j++) fv[j] = (j == basis) ? 0.0f : NEGV;

    const int l0    = (chunk == 0) ? 1 : chunk * 8;
    const int steps = (chunk == 0) ? 7 : 8;
    for (int s = 0; s < steps; s++) {
        const int l = l0 + s;
        float fn[NC];
        #pragma unroll
        for (int j = 0; j < NC; j++) {
            fn[j] = lse5(fv[0] + TR[j*NC+0], fv[1] + TR[j*NC+1], fv[2] + TR[j*NC+2],
                         fv[3] + TR[j*NC+3], fv[4] + TR[j*NC+4]) + E[l*NT + j];
        }
        #pragma unroll
        for (int j = 0; j < NC; j++) fv[j] = fn[j];
    }
    __syncthreads();
    #pragma unroll
    for (int j = 0; j < NC; j++) E[chunk*25 + basis*NC + j] = fv[j];

    int n = 64, cur = 0;
    while (n > 1) {
        __syncthreads();
        const float* in = (cur == 0) ? (const float*)E : (const float*)M2;
        float*       ob = (cur == 0) ? M2 : E;
        const int half = n >> 1;
        for (int e2 = tid; e2 < half*25; e2 += 320) {
            const int p = e2 / 25, r = e2 - p*25;
            const int i = r / NC, j = r - (r/NC)*NC;
            const float* A  = in + (2*p)*25 + i*NC;
            const float* Bm = in + (2*p + 1)*25 + j;
            ob[p*25 + r] = lse5(A[0] + Bm[0], A[1] + Bm[NC], A[2] + Bm[2*NC],
                                A[3] + Bm[3*NC], A[4] + Bm[4*NC]);
        }
        cur ^= 1; n = half;
    }
    __syncthreads();

    if (tid == 0) {
        float gg = gred[0] + gred[1] + gred[2] + gred[3] + gred[4];
        const float* M = (cur == 0) ? (const float*)E : (const float*)M2;
        float v[NC];
        #pragma unroll
        for (int j = 0; j < NC; j++)
            v[j] = lse5(u_sh[0] + M[0*NC+j], u_sh[1] + M[1*NC+j], u_sh[2] + M[2*NC+j],
                        u_sh[3] + M[3*NC+j], u_sh[4] + M[4*NC+j]);
        float fwd = lse5(v[0] + T[STOP_TAG*NT+0], v[1] + T[STOP_TAG*NT+1],
                         v[2] + T[STOP_TAG*NT+2], v[3] + T[STOP_TAG*NT+3],
                         v[4] + T[STOP_TAG*NT+4]);
        atomicAdd(score, fwd - gg);
    }
}

extern "C" void kernel_launch(void* const* d_in, const int* in_sizes, int n_in,
                              void* d_out, int out_size, void* d_ws, size_t ws_size,
                              hipStream_t stream) {
    const float* X     = (const float*)d_in[0];   // fuse_embeddings [32768,1024]
    const int*   lab   = (const int*)  d_in[1];   // label_class [32768]
    const float* W     = (const float*)d_in[2];   // [7,1024]
    const float* bvec  = (const float*)d_in[3];   // [7]
    const float* trans = (const float*)d_in[4];   // [7,7]
    float* out = (float*)d_out;
    float* wsf = (float*)d_ws;

    if (wsf != nullptr && ws_size >= (size_t)WS_TOT * sizeof(float)) {
        k_fused<<<FGRID, FBLK, 0, stream>>>(X, W, bvec, lab, trans, out, wsf);
        return;
    }

    // Fallback: proven two-kernel path (ws unavailable)
    k_logits<<<GRID_LOGITS, 256, 0, stream>>>(X, W, bvec, lab, out);
    k_crf<<<BSEQ, 320, 0, stream>>>(out, lab, trans, out);
}

// Round 10
// 212.758 us; speedup vs baseline: 1.3302x; 1.3302x over previous
//
#include <hip/hip_runtime.h>

// Problem constants
#define BSEQ 64
#define LSEQ 512
#define CCH  1024
#define NT   7            // NUM_TAGS
#define NC   5            // real classes (labels are always 0..4)
#define NTOK (BSEQ*LSEQ)  // 32768
#define START_TAG 5
#define STOP_TAG  6
#define NEGV (-10000.0f)
#define GRID_LOGITS 1024  // k_logits assumes exactly this grid (4 iters/wave)

// R13: REVERT to the best-measured kernel (R1 = prior session's 209.7us,
// measured 211.4us here). Session decomposition (R7/R8 multi-launch
// measurements): window = fills ~156 (harness) + tL 20.4 (= 128MB/6.3TB/s
// stream FLOOR) + g 8.7 (dispatch-boundary, harness/runtime-owned) + tC 2.8
// (structural CRF cost). Controllable prize was g+tC ~ 11.5us; three fusion
// designs (cooperative R6, spin-flags R7, zero-wait R9) all cost ~100us in
// device-scope atomic/fence machinery (non-coherent per-XCD L2 -> every
// device-scope op round-trips the coherence point; R7/R9 identical ~127us
// with opposite sync policies proves the machinery, not the waiting, is the
// cost). Fusion abandoned; this is the achievable floor.
typedef float vfloat4 __attribute__((ext_vector_type(4)));

// ---------------- DPP wave64 sum (result lands in lane 63) ----------------
template<int CTRL, int RMASK, int BMASK>
__device__ __forceinline__ float dpp_add(float x) {
    int y = __builtin_amdgcn_update_dpp(0, __float_as_int(x), CTRL, RMASK, BMASK, true);
    return x + __int_as_float(y);
}
__device__ __forceinline__ float wave_sum(float x) {
    x = dpp_add<0x111, 0xF, 0xF>(x);  // row_shr:1
    x = dpp_add<0x112, 0xF, 0xF>(x);  // row_shr:2
    x = dpp_add<0x114, 0xF, 0xF>(x);  // row_shr:4
    x = dpp_add<0x118, 0xF, 0xF>(x);  // row_shr:8  -> lane15 of each row16 has row sum
    x = dpp_add<0x142, 0xA, 0xF>(x);  // row_bcast:15 into rows 1,3
    x = dpp_add<0x143, 0xC, 0xF>(x);  // row_bcast:31 into rows 2,3 -> lane63 = total
    return x;
}

// 5-way log-sum-exp helper
__device__ __forceinline__ float lse5(const float v0, const float v1, const float v2,
                                      const float v3, const float v4) {
    float m = fmaxf(fmaxf(fmaxf(v0, v1), fmaxf(v2, v3)), v4);
    float s = __expf(v0 - m) + __expf(v1 - m) + __expf(v2 - m)
            + __expf(v3 - m) + __expf(v4 - m);
    return m + __logf(s);
}

// ---------------- Kernel 1: logits (X @ W^T + b), labels copy, score zero ----------------
// 2 rows/iter, 4 iters/wave, fully-unrolled ping-pong register prefetch
// (next iter's 8 float4 issued before current compute) + nontemporal X loads.
// Measured at the HBM stream floor (tL = 20.4us = 128MB / 6.3TB/s, R7).
__global__ __launch_bounds__(256)
void k_logits(const float* __restrict__ X, const float* __restrict__ W,
              const float* __restrict__ bvec, const int* __restrict__ lab,
              float* __restrict__ out)
{
    __shared__ float Wl[NT][CCH];   // 28 KB
    __shared__ float bl[NT];
    {
        const vfloat4* W4  = (const vfloat4*)W;
        vfloat4*       Wl4 = (vfloat4*)(&Wl[0][0]);
        for (int i = threadIdx.x; i < NT*CCH/4; i += 256) Wl4[i] = W4[i];
        if (threadIdx.x < NT) bl[threadIdx.x] = bvec[threadIdx.x];
    }
    __syncthreads();

    const int lane = threadIdx.x & 63;
    const int wid  = (blockIdx.x * 256 + threadIdx.x) >> 6;
    const int nw   = (GRID_LOGITS * 256) >> 6;      // 4096 waves
    float* outP = out + 1 + NTOK;

    vfloat4 xv[2][2][4];   // [buf][row][k]  -- static indices after full unroll

    // prologue: load iteration 0 into buf 0
    {
        const size_t r0 = (size_t)wid * 2;
        const vfloat4* x0 = (const vfloat4*)(X + r0 * CCH);
        const vfloat4* x1 = (const vfloat4*)(X + (r0 + 1) * CCH);
        #pragma unroll
        for (int k = 0; k < 4; k++) {
            xv[0][0][k] = __builtin_nontemporal_load(&x0[k*64 + lane]);
            xv[0][1][k] = __builtin_nontemporal_load(&x1[k*64 + lane]);
        }
    }

    #pragma unroll
    for (int it = 0; it < 4; ++it) {
        const int buf = it & 1;
        // prefetch next iteration before touching current buffer
        if (it < 3) {
            const size_t rn = (size_t)(wid + (it + 1) * nw) * 2;
            const vfloat4* x0 = (const vfloat4*)(X + rn * CCH);
            const vfloat4* x1 = (const vfloat4*)(X + (rn + 1) * CCH);
            #pragma unroll
            for (int k = 0; k < 4; k++) {
                xv[buf ^ 1][0][k] = __builtin_nontemporal_load(&x0[k*64 + lane]);
                xv[buf ^ 1][1][k] = __builtin_nontemporal_load(&x1[k*64 + lane]);
            }
        }

        float acc[2][NT];
        #pragma unroll
        for (int r = 0; r < 2; r++)
            #pragma unroll
            for (int t = 0; t < NT; t++) acc[r][t] = 0.0f;

        #pragma unroll
        for (int k = 0; k < 4; k++) {
            const int cb = (k*64 + lane) * 4;
            #pragma unroll
            for (int t = 0; t < NT; t++) {
                const vfloat4 wv = *(const vfloat4*)(&Wl[t][cb]);   // unit-stride b128, conflict-free
                #pragma unroll
                for (int r = 0; r < 2; r++) {
                    acc[r][t] = fmaf(xv[buf][r][k].x, wv.x,
                                fmaf(xv[buf][r][k].y, wv.y,
                                fmaf(xv[buf][r][k].z, wv.z,
                                fmaf(xv[buf][r][k].w, wv.w, acc[r][t]))));
                }
            }
        }

        const size_t base = (size_t)(wid + it * nw) * 2;
        #pragma unroll
        for (int r = 0; r < 2; r++) {
            #pragma unroll
            for (int t = 0; t < NT; t++) {
                float s = wave_sum(acc[r][t]);
                if (lane == 63) outP[(base + r) * NT + t] = s + bl[t];
            }
        }
    }

    // labels as float + zero the score slot
    for (int i = blockIdx.x * 256 + threadIdx.x; i < NTOK; i += GRID_LOGITS * 256)
        out[1 + i] = (float)lab[i];
    if (blockIdx.x == 0 && threadIdx.x == 0) out[0] = 0.0f;
}

// ---------------- Kernel 2: CRF NLL, 5-class log-semiring chunked scan ----------------
// transitions[START,:]=NEG and [:,STOP]=NEG make the recurrence exactly 5x5 in
// fp32 (START enters only via step-0 injection u[k]=T[k,START]+e0[k]; STOP only
// at the final fold; all other START/STOP terms are exp(-10000-m) == 0.0f).
// Chunk 0 covers steps 1..7, chunks 1..63 cover 8 steps. 64 blocks x 320 thr
// (= 64 chunks x 5 basis). Tree-combine 64 5x5 matrices, fold u and T[STOP,:].
// Measured tC ~ 2.8us (R8) -- structural cost, not worth further work.
__global__ __launch_bounds__(320)
void k_crf(const float* __restrict__ dout_ro, const int* __restrict__ lab,
           const float* __restrict__ trans, float* __restrict__ score)
{
    __shared__ float E[LSEQ*NT];   // 3584 floats; reused as matrix buffer A after recurrence
    __shared__ float M2[32*25];    // ping-pong buffer B
    __shared__ float T[49];
    __shared__ float u_sh[NC];     // fv after step 0 (START injection)
    __shared__ float gred[5];

    const int b   = blockIdx.x;
    const int tid = threadIdx.x;
    const float* feats = dout_ro + 1 + NTOK + (size_t)b * (LSEQ*NT);

    for (int i = tid; i < LSEQ*NT; i += 320) E[i] = feats[i];
    if (tid < 49) T[tid] = trans[tid];
    __syncthreads();

    if (tid < NC) u_sh[tid] = T[tid*NT + START_TAG] + E[tid];   // e0[k] before E is overwritten

    // ---- gold score (parallel over tokens) ----
    float g = 0.0f;
    for (int l = tid; l < LSEQ; l += 320) {
        const int t  = lab[b*LSEQ + l];
        const int tp = (l == 0) ? START_TAG : lab[b*LSEQ + l - 1];
        g += E[l*NT + t] + T[t*NT + tp];
    }
    if (tid == 0) g += T[STOP_TAG*NT + lab[b*LSEQ + LSEQ - 1]];
    {
        float gs = wave_sum(g);
        if ((tid & 63) == 63) gred[tid >> 6] = gs;
    }

    // ---- chunk basis recurrences (5x5, all in registers) ----
    float TR[NC*NC];
    #pragma unroll
    for (int j = 0; j < NC; j++)
        #pragma unroll
        for (int k = 0; k < NC; k++) TR[j*NC + k] = T[j*NT + k];

    const int chunk = tid / NC;
    const int basis = tid - chunk * NC;
    float fv[NC];
    #pragma unroll
    for (int j = 0; j < NC; j++) fv[j] = (j == basis) ? 0.0f : NEGV;

    const int l0    = (chunk == 0) ? 1 : chunk * 8;
    const int steps = (chunk == 0) ? 7 : 8;
    for (int s = 0; s < steps; s++) {
        const int l = l0 + s;
        float fn[NC];
        #pragma unroll
        for (int j = 0; j < NC; j++) {
            fn[j] = lse5(fv[0] + TR[j*NC+0], fv[1] + TR[j*NC+1], fv[2] + TR[j*NC+2],
                         fv[3] + TR[j*NC+3], fv[4] + TR[j*NC+4]) + E[l*NT + j];
        }
        #pragma unroll
        for (int j = 0; j < NC; j++) fv[j] = fn[j];
    }
    __syncthreads();   // all E reads done; safe to overwrite with matrices
    #pragma unroll
    for (int j = 0; j < NC; j++) E[chunk*25 + basis*NC + j] = fv[j];

    // ---- tree combine: C[i][j] = lse_k(A[i][k] + B[k][j]), chronological L->R ----
    int n = 64, cur = 0;
    while (n > 1) {
        __syncthreads();
        const float* in = (cur == 0) ? (const float*)E : (const float*)M2;
        float*       ob = (cur == 0) ? M2 : E;
        const int half = n >> 1;
        for (int e2 = tid; e2 < half*25; e2 += 320) {
            const int p = e2 / 25, r = e2 - p*25;
            const int i = r / NC, j = r - (r/NC)*NC;
            const float* A  = in + (2*p)*25 + i*NC;
            const float* Bm = in + (2*p + 1)*25 + j;
            ob[p*25 + r] = lse5(A[0] + Bm[0], A[1] + Bm[NC], A[2] + Bm[2*NC],
                                A[3] + Bm[3*NC], A[4] + Bm[4*NC]);
        }
        cur ^= 1; n = half;
    }
    __syncthreads();

    if (tid == 0) {
        float gg = gred[0] + gred[1] + gred[2] + gred[3] + gred[4];
        const float* M = (cur == 0) ? (const float*)E : (const float*)M2;  // final 5x5
        float v[NC];
        #pragma unroll
        for (int j = 0; j < NC; j++)
            v[j] = lse5(u_sh[0] + M[0*NC+j], u_sh[1] + M[1*NC+j], u_sh[2] + M[2*NC+j],
                        u_sh[3] + M[3*NC+j], u_sh[4] + M[4*NC+j]);
        float fwd = lse5(v[0] + T[STOP_TAG*NT+0], v[1] + T[STOP_TAG*NT+1],
                         v[2] + T[STOP_TAG*NT+2], v[3] + T[STOP_TAG*NT+3],
                         v[4] + T[STOP_TAG*NT+4]);
        atomicAdd(score, fwd - gg);
    }
}

extern "C" void kernel_launch(void* const* d_in, const int* in_sizes, int n_in,
                              void* d_out, int out_size, void* d_ws, size_t ws_size,
                              hipStream_t stream) {
    const float* X     = (const float*)d_in[0];   // fuse_embeddings [32768,1024]
    const int*   lab   = (const int*)  d_in[1];   // label_class [32768]
    const float* W     = (const float*)d_in[2];   // [7,1024]
    const float* bvec  = (const float*)d_in[3];   // [7]
    const float* trans = (const float*)d_in[4];   // [7,7]
    float* out = (float*)d_out;

    k_logits<<<GRID_LOGITS, 256, 0, stream>>>(X, W, bvec, lab, out);
    k_crf<<<BSEQ, 320, 0, stream>>>(out, lab, trans, out);
}